// Round 4
// baseline (159.267 us; speedup 1.0000x reference)
//
#include <hip/hip_runtime.h>
#include <hip/hip_bf16.h>
#include <stdint.h>

// ---- problem constants ----
#define B_   8
#define SQ_  512
#define SK_  512
#define H_   768
#define NH_  12
#define DH_  64
#define BH_  (B_*NH_)          // 96 (b,h) pairs
#define M_   (B_*SQ_)          // 4096 rows for both hidden and context
#define NTOT (3*H_)            // 2304 fused QKV output columns

typedef __attribute__((ext_vector_type(8))) short short8;
typedef __attribute__((ext_vector_type(4))) float floatx4;
typedef __attribute__((ext_vector_type(4))) unsigned int uint4v;
typedef __attribute__((ext_vector_type(4))) unsigned short ushort4v;

#define MFMA16(a, b, c) __builtin_amdgcn_mfma_f32_16x16x32_bf16((a), (b), (c), 0, 0, 0)

__device__ __forceinline__ unsigned short f2b(float f) {   // fp32 -> bf16 bits (RNE)
  union { __hip_bfloat16 h; unsigned short u; } c;
  c.h = __float2bfloat16(f);
  return c.u;
}
__device__ __forceinline__ float b2f(unsigned short u) {   // bf16 bits -> fp32
  union { float f; unsigned u; } c; c.u = ((unsigned)u) << 16;
  return c.f;
}
__device__ __forceinline__ short8 ld8(const unsigned short* p) {  // 16B vector load
  union { uint4v u; short8 s; } c;
  c.u = *(const uint4v*)p;
  return c.s;
}
// 2 fp32 -> packed 2x bf16 (one v_cvt_pk_bf16_f32)
__device__ __forceinline__ unsigned cvt2(float a, float b) {
  union { __hip_bfloat162 h; unsigned u; } c;
  c.h = __float22bfloat162_rn(float2{a, b});
  return c.u;
}
// 4 fp32 -> 4 bf16 (two v_cvt_pk_bf16_f32)
__device__ __forceinline__ ushort4v cvt4(floatx4 v) {
  union { unsigned u[2]; ushort4v s; } c;
  c.u[0] = cvt2(v.x, v.y);
  c.u[1] = cvt2(v.z, v.w);
  return c.s;
}
// async global->LDS, 16B per lane, lane-contiguous destination (m97 pattern)
__device__ __forceinline__ void gl_lds16(const unsigned short* g, unsigned short* l) {
  __builtin_amdgcn_global_load_lds(
      (const __attribute__((address_space(1))) unsigned int*)g,
      (__attribute__((address_space(3))) unsigned int*)l, 16, 0, 0);
}

// ---------------------------------------------------------------------------
// Kernel 1: pack fp32 inputs -> bf16 workspace. Restored: halves the GEMM's
// cache-level re-read traffic (452 MB fp32 -> 221 MB bf16), which rounds 2-3
// showed is the GEMM's binding resource.
// ---------------------------------------------------------------------------
#define SEG_X   (M_*H_)          // 3145728 (hidden)
#define SEG_XC  (2*SEG_X)        // 6291456 (end of context)
#define SEG_W1  (H_*H_)          // 589824
#define SEG_WE  (SEG_XC + 3*SEG_W1)   // 8060928
#define SEG_BE  (SEG_WE + NTOT)  // 8063232
#define SEG_PE  (SEG_BE + SQ_*DH_)    // 8096000 (pos bf16)

__global__ __launch_bounds__(256) void pack_kernel(
    const float* __restrict__ hid, const float* __restrict__ ctx,
    const float* __restrict__ Wq, const float* __restrict__ Wk, const float* __restrict__ Wv,
    const float* __restrict__ bq, const float* __restrict__ bk, const float* __restrict__ bv,
    const float* __restrict__ pos,
    unsigned short* __restrict__ Xh, unsigned short* __restrict__ Xc,
    unsigned short* __restrict__ Wa, float* __restrict__ Ba,
    unsigned short* __restrict__ Pb)
{
  int i = (blockIdx.x * 256 + threadIdx.x) * 4;
  if (i < SEG_X) {
    floatx4 v = *(const floatx4*)(hid + i);
    *(ushort4v*)(Xh + i) = cvt4(v);
  } else if (i < SEG_XC) {
    int j = i - SEG_X;
    floatx4 v = *(const floatx4*)(ctx + j);
    *(ushort4v*)(Xc + j) = cvt4(v);
  } else if (i < SEG_WE) {
    int j = i - SEG_XC;
    const float* src; int o;
    if (j < SEG_W1)        { src = Wq; o = j; }
    else if (j < 2*SEG_W1) { src = Wk; o = j - SEG_W1; }
    else                   { src = Wv; o = j - 2*SEG_W1; }
    floatx4 v = *(const floatx4*)(src + o);
    *(ushort4v*)(Wa + j) = cvt4(v);
  } else if (i < SEG_BE) {
    int j = i - SEG_WE;
    #pragma unroll
    for (int t = 0; t < 4; ++t) {
      int jj = j + t;
      float v = (jj < H_) ? bq[jj] : (jj < 2*H_) ? bk[jj - H_] : bv[jj - 2*H_];
      Ba[jj] = v;
    }
  } else if (i < SEG_PE) {
    int j = i - SEG_BE;
    floatx4 v = *(const floatx4*)(pos + j);
    *(ushort4v*)(Pb + j) = cvt4(v);
  }
}

// ---------------------------------------------------------------------------
// Kernel 2: fused QKV projection GEMM (bf16 MFMA), M=4096 x N=2304 x K=768.
//   2-phase double-buffered global_load_lds pipeline (T3-minimum recipe):
//   stage tile t+1 into buf^1 (async) BEFORE computing tile t; single
//   __syncthreads (vmcnt drain) per K-step. Linear LDS dest required by
//   gload_lds; rule-21 chunk-XOR swizzle (chunk ^= row&7) applied to the
//   per-lane GLOBAL source and the ds_read column (same involution) to
//   avoid the 16-way ds_read_b128 bank conflict.
//   XCD-swizzled tile mapping (8 regions of 8bm x 9bn; region = bx&7).
// ---------------------------------------------------------------------------
__global__ __launch_bounds__(256) void qkv_gemm(
    const unsigned short* __restrict__ Xh, const unsigned short* __restrict__ Xc,
    const unsigned short* __restrict__ W,  const float* __restrict__ bias,
    const unsigned short* __restrict__ Pb,
    unsigned short* __restrict__ qw, unsigned short* __restrict__ kw,
    unsigned short* __restrict__ vt)
{
  __shared__ unsigned short As[2][128][64];   // X tiles, double-buffered
  __shared__ unsigned short Bs[2][128][64];   // W tiles, double-buffered

  int bx = blockIdx.x;
  int xcd = bx & 7, j = bx >> 3;            // j in [0,72)
  int bm = (xcd >> 1) * 8 + j / 9;          // 32 m-tiles
  int bn = (xcd & 1) * 9 + j % 9;           // 18 n-tiles
  const unsigned short* X = (bn < 6) ? Xh : Xc;
  bool isV = (bn >= 12);
  int m0 = bm * 128, n0 = bn * 128;

  int tid = threadIdx.x;
  int lane = tid & 63, wave = tid >> 6;
  int wm = (wave & 1) * 64, wn = (wave >> 1) * 64;
  int lc16 = lane & 15, quad = lane >> 4, kk = quad * 8;

  // staging coords: each wave stages 32 rows; per gload_lds: 8 rows x 64 cols
  int srow = lane >> 3;                 // 0..7 row within 8-row stripe
  int swz  = (lane & 7) ^ srow;         // pre-swizzled source chunk (involution)
  int rb   = wave * 32;

  int oa = isV ? wm : wn;
  int ob = isV ? wn : wm;

  floatx4 acc[4][4];
  #pragma unroll
  for (int i = 0; i < 4; ++i)
    #pragma unroll
    for (int jj = 0; jj < 4; ++jj) acc[i][jj] = (floatx4){0.f, 0.f, 0.f, 0.f};

  // prologue: stage K-tile 0 into buffer 0
  #pragma unroll
  for (int c = 0; c < 4; ++c) {
    int r = rb + c * 8;
    gl_lds16(&X[(m0 + r + srow) * H_ + swz * 8], &As[0][r][0]);
    gl_lds16(&W[(n0 + r + srow) * H_ + swz * 8], &Bs[0][r][0]);
  }
  __syncthreads();   // drains vmcnt(0): tile 0 ready

  for (int t = 0; t < 12; ++t) {
    int cur = t & 1;
    if (t < 11) {    // async stage of next K-tile into the other buffer
      int k0n = (t + 1) * 64;
      #pragma unroll
      for (int c = 0; c < 4; ++c) {
        int r = rb + c * 8;
        gl_lds16(&X[(m0 + r + srow) * H_ + k0n + swz * 8], &As[cur ^ 1][r][0]);
        gl_lds16(&W[(n0 + r + srow) * H_ + k0n + swz * 8], &Bs[cur ^ 1][r][0]);
      }
    }

    unsigned short (*Acur)[64] = As[cur];
    unsigned short (*Bcur)[64] = Bs[cur];
    unsigned short (*TA)[64] = isV ? Acur : Bcur;
    unsigned short (*TB)[64] = isV ? Bcur : Acur;

    #pragma unroll
    for (int s = 0; s < 2; ++s) {
      short8 af[4], bf[4];
      int key = lc16 & 7;                         // row&7 for all frag rows
      int cswz = ((s * 4 + quad) ^ key) * 8;      // swizzled column (in shorts)
      #pragma unroll
      for (int i = 0; i < 4; ++i) af[i] = ld8(&TA[oa + i * 16 + lc16][cswz]);
      #pragma unroll
      for (int i = 0; i < 4; ++i) bf[i] = ld8(&TB[ob + i * 16 + lc16][cswz]);
      #pragma unroll
      for (int mi = 0; mi < 4; ++mi)
        #pragma unroll
        for (int ni = 0; ni < 4; ++ni)
          acc[mi][ni] = MFMA16(af[mi], bf[ni], acc[mi][ni]);
    }
    __syncthreads();   // drain staged loads + tile consumed; flip buffers
  }

  if (!isV) {
    #pragma unroll
    for (int mi = 0; mi < 4; ++mi) {
      #pragma unroll
      for (int ni = 0; ni < 4; ++ni) {
        int gn0 = n0 + wn + mi * 16 + quad * 4;     // 4 consecutive features
        int gs  = m0 + wm + ni * 16 + lc16;         // sequence index
        int bidx = gs >> 9, s0 = gs & 511;
        floatx4 bv4 = *(const floatx4*)&bias[gn0];
        if (gn0 < H_) {                              // Q
          int h = gn0 >> 6, d0 = gn0 & 63;
          floatx4 v;
          #pragma unroll
          for (int r = 0; r < 4; ++r) v[r] = acc[mi][ni][r] + bv4[r];
          *(ushort4v*)(qw + (((bidx * NH_ + h) << 9) + s0) * DH_ + d0) = cvt4(v);
        } else {                                     // K (+ bf16 pos_k)
          int g = gn0 - H_;
          int h = g >> 6, d0 = g & 63;
          ushort4v pk = *(const ushort4v*)(Pb + s0 * DH_ + d0);
          floatx4 v;
          #pragma unroll
          for (int r = 0; r < 4; ++r) v[r] = acc[mi][ni][r] + bv4[r] + b2f(pk[r]);
          *(ushort4v*)(kw + (((bidx * NH_ + h) << 9) + s0) * DH_ + d0) = cvt4(v);
        }
      }
    }
  } else {
    #pragma unroll
    for (int mi = 0; mi < 4; ++mi) {
      #pragma unroll
      for (int ni = 0; ni < 4; ++ni) {
        int gm0 = m0 + wm + mi * 16 + quad * 4;
        int gn  = n0 + wn + ni * 16 + lc16;
        float bvs = bias[gn];
        int bidx = gm0 >> 9, s0 = gm0 & 511;
        int g = gn - 2 * H_;
        int h = g >> 6, d = g & 63;
        floatx4 v;
        #pragma unroll
        for (int r = 0; r < 4; ++r) v[r] = acc[mi][ni][r] + bvs;
        *(ushort4v*)(vt + ((bidx * NH_ + h) * DH_ + d) * SK_ + s0) = cvt4(v);
      }
    }
  }
}

// ---------------------------------------------------------------------------
// Kernel 3: attention (frozen this round), softmax fused into QK epilogue.
// ---------------------------------------------------------------------------
#define SCALE2 0.18033688011112042f   // (1/8) * log2(e)
#define CPAD 136                      // chunk row stride (128 + 8)

__global__ __launch_bounds__(256) void attn_kernel(
    const unsigned short* __restrict__ qw, const unsigned short* __restrict__ kw,
    const unsigned short* __restrict__ vt, const unsigned short* __restrict__ posb,
    const int* __restrict__ mask, float* __restrict__ out)
{
  __shared__ unsigned short Sc[2][64][CPAD];  // bf16 probs, double-buffered chunks
  __shared__ float mb2[SK_];                  // mask bias in exp2 domain
  __shared__ float red[64][4];                // per-wave row-sum partials

  int bx = blockIdx.x;
  int bh = bx % 96, qt = bx / 96;          // XCD-friendly: bx%8 == bh%8
  int b = bh / NH_, h = bh - b * NH_;
  int tid = threadIdx.x, lane = tid & 63, wave = tid >> 6;
  int lc16 = lane & 15, quad = lane >> 4, kk = quad * 8;

  for (int i = tid; i < SK_; i += 256)
    mb2[i] = mask[(b << 9) + i] ? 0.0f : -100000.0f;

  // B-operand frags (held all QK phases): 4 row-tiles x (2 q + 2 pos_q)
  const unsigned short* qbase = qw + ((bh << 9) + qt * 64) * DH_;
  const unsigned short* pqb   = posb + (qt * 64) * DH_;
  short8 aq[4][2], ap[4][2];
  #pragma unroll
  for (int rt = 0; rt < 4; ++rt) {
    const unsigned short* qr = qbase + (rt * 16 + lc16) * DH_;
    const unsigned short* pr = pqb + (rt * 16 + lc16) * DH_;
    aq[rt][0] = ld8(qr + kk);
    aq[rt][1] = ld8(qr + 32 + kk);
    ap[rt][0] = ld8(pr + kk);
    ap[rt][1] = ld8(pr + 32 + kk);
  }

  const unsigned short* kwb = kw + ((bh << 9)) * DH_;
  const unsigned short* vb0 = vt + (bh * DH_ + wave * 16 + lc16) * SK_;
  float rs[4] = {0.f, 0.f, 0.f, 0.f};      // per-lane row-sum partials
  floatx4 o[4];
  #pragma unroll
  for (int i = 0; i < 4; ++i) o[i] = (floatx4){0.f, 0.f, 0.f, 0.f};

  // prefetch K/pos step 0
  short8 cb0, cb1, cp0, cp1, nb0, nb1, np0, np1;
  {
    int kcol = wave * 32;
    const unsigned short* kb = kwb + kcol * DH_;
    const unsigned short* pb = posb + kcol * DH_;
    cb0 = ld8(kb + lc16 * DH_ + kk);
    cb1 = ld8(kb + lc16 * DH_ + 32 + kk);
    cp0 = ld8(pb + lc16 * DH_ + kk);
    cp1 = ld8(pb + lc16 * DH_ + 32 + kk);
  }

  __syncthreads();   // mb2 ready

  for (int chunk = 0; chunk < 4; ++chunk) {
    unsigned short (*S)[CPAD] = Sc[chunk & 1];

    // V frags for this chunk: issue early, consumed after the barrier
    short8 vf[4];
    #pragma unroll
    for (int ks = 0; ks < 4; ++ks) vf[ks] = ld8(vb0 + chunk * 128 + ks * 32 + kk);

    // ---- QK + exp: wave owns chunk-local cols [wave*32, wave*32+32) ----
    #pragma unroll
    for (int ct = 0; ct < 2; ++ct) {
      int s = chunk * 2 + ct;
      if (s < 7) {   // prefetch next step's K/pos frags
        int kcol = ((s + 1) >> 1) * 128 + wave * 32 + ((s + 1) & 1) * 16;
        const unsigned short* kb = kwb + kcol * DH_;
        const unsigned short* pb = posb + kcol * DH_;
        nb0 = ld8(kb + lc16 * DH_ + kk);
        nb1 = ld8(kb + lc16 * DH_ + 32 + kk);
        np0 = ld8(pb + lc16 * DH_ + kk);
        np1 = ld8(pb + lc16 * DH_ + 32 + kk);
      }
      int kcol = chunk * 128 + wave * 32 + ct * 16;
      floatx4 mk = *(const floatx4*)&mb2[kcol + quad * 4];
      floatx4 c[4];
      __builtin_amdgcn_s_setprio(1);
      #pragma unroll
      for (int rt = 0; rt < 4; ++rt) {
        c[rt] = (floatx4){0.f, 0.f, 0.f, 0.f};
        c[rt] = MFMA16(cb0, aq[rt][0], c[rt]);   // A=K-tile, B=Q-rows
        c[rt] = MFMA16(cb1, aq[rt][1], c[rt]);
        c[rt] = MFMA16(cp0, ap[rt][0], c[rt]);
        c[rt] = MFMA16(cp1, ap[rt][1], c[rt]);
      }
      __builtin_amdgcn_s_setprio(0);
      int lcol = wave * 32 + ct * 16 + quad * 4;   // chunk-local col base
      #pragma unroll
      for (int rt = 0; rt < 4; ++rt) {
        ushort4v pv;
        float sum = 0.f;
        #pragma unroll
        for (int r = 0; r < 4; ++r) {
          float e = __builtin_exp2f(c[rt][r] * SCALE2 + mk[r]);
          sum += e;
          pv[r] = f2b(e);
        }
        rs[rt] += sum;
        *(ushort4v*)&S[rt * 16 + lc16][lcol] = pv;
      }
      cb0 = nb0; cb1 = nb1; cp0 = np0; cp1 = np1;
    }
    __syncthreads();   // probs chunk ready (also: prior chunk fully consumed)

    // ---- PV over this chunk: wave owns d-slice [wave*16, +16) ----
    __builtin_amdgcn_s_setprio(1);
    #pragma unroll
    for (int ks = 0; ks < 4; ++ks) {
      #pragma unroll
      for (int rt = 0; rt < 4; ++rt) {
        short8 pa = ld8(&S[rt * 16 + lc16][ks * 32 + kk]);
        o[rt] = MFMA16(pa, vf[ks], o[rt]);
      }
    }
    __builtin_amdgcn_s_setprio(0);
    // no second barrier: next chunk writes the other Sc buffer
  }

  // ---- row-sum: reduce across quads, then across waves via LDS ----
  #pragma unroll
  for (int rt = 0; rt < 4; ++rt) {
    rs[rt] += __shfl_xor(rs[rt], 16, 64);
    rs[rt] += __shfl_xor(rs[rt], 32, 64);
  }
  if (quad == 0) {
    #pragma unroll
    for (int rt = 0; rt < 4; ++rt) red[rt * 16 + lc16][wave] = rs[rt];
  }
  __syncthreads();

  #pragma unroll
  for (int rt = 0; rt < 4; ++rt) {
    #pragma unroll
    for (int r = 0; r < 4; ++r) {
      int sl = rt * 16 + quad * 4 + r;
      float inv = 1.0f / (red[sl][0] + red[sl][1] + red[sl][2] + red[sl][3]);
      int s = qt * 64 + sl;
      out[((b << 9) + s) * H_ + h * DH_ + wave * 16 + lc16] = o[rt][r] * inv;
    }
  }
}

// ---------------------------------------------------------------------------
// host launcher
// ---------------------------------------------------------------------------
extern "C" void kernel_launch(void* const* d_in, const int* in_sizes, int n_in,
                              void* d_out, int out_size, void* d_ws, size_t ws_size,
                              hipStream_t stream) {
  (void)in_sizes; (void)n_in; (void)out_size; (void)ws_size;
  const float* hid  = (const float*)d_in[0];
  const float* ctx  = (const float*)d_in[1];
  const int*   mask = (const int*)d_in[2];
  const float* Wq   = (const float*)d_in[3];
  const float* bq   = (const float*)d_in[4];
  const float* Wk   = (const float*)d_in[5];
  const float* bk   = (const float*)d_in[6];
  const float* Wv   = (const float*)d_in[7];
  const float* bv   = (const float*)d_in[8];
  const float* pos  = (const float*)d_in[9];

  char* ws = (char*)d_ws;
  size_t off = 0;
  auto alloc = [&](size_t bytes) { char* p = ws + off; off = (off + bytes + 255) & ~(size_t)255; return p; };
  unsigned short* Xh = (unsigned short*)alloc((size_t)SEG_X * 2);
  unsigned short* Xc = (unsigned short*)alloc((size_t)SEG_X * 2);
  unsigned short* Wa = (unsigned short*)alloc((size_t)3 * SEG_W1 * 2);
  float*          Ba = (float*)alloc((size_t)NTOT * 4);
  unsigned short* qw = (unsigned short*)alloc((size_t)BH_ * SQ_ * DH_ * 2);
  unsigned short* kw = (unsigned short*)alloc((size_t)BH_ * SK_ * DH_ * 2);
  unsigned short* vt = (unsigned short*)alloc((size_t)BH_ * DH_ * SK_ * 2);
  unsigned short* Pb = (unsigned short*)alloc((size_t)SQ_ * DH_ * 2);

  int pack_blocks = (SEG_PE / 4 + 255) / 256;
  pack_kernel<<<pack_blocks, 256, 0, stream>>>(hid, ctx, Wq, Wk, Wv, bq, bk, bv, pos, Xh, Xc, Wa, Ba, Pb);
  qkv_gemm<<<32 * 18, 256, 0, stream>>>(Xh, Xc, Wa, Ba, Pb, qw, kw, vt);
  attn_kernel<<<BH_ * 8, 256, 0, stream>>>(qw, kw, vt, Pb, mask, (float*)d_out);
}

// Round 5
// 155.411 us; speedup vs baseline: 1.0248x; 1.0248x over previous
//
#include <hip/hip_runtime.h>
#include <hip/hip_bf16.h>
#include <stdint.h>

// ---- problem constants ----
#define B_   8
#define SQ_  512
#define SK_  512
#define H_   768
#define NH_  12
#define DH_  64
#define BH_  (B_*NH_)          // 96 (b,h) pairs
#define M_   (B_*SQ_)          // 4096 rows for both hidden and context
#define NTOT (3*H_)            // 2304 fused QKV output columns

typedef __attribute__((ext_vector_type(8))) short short8;
typedef __attribute__((ext_vector_type(4))) float floatx4;
typedef __attribute__((ext_vector_type(4))) unsigned int uint4v;
typedef __attribute__((ext_vector_type(4))) unsigned short ushort4v;

#define MFMA16(a, b, c) __builtin_amdgcn_mfma_f32_16x16x32_bf16((a), (b), (c), 0, 0, 0)

__device__ __forceinline__ unsigned short f2b(float f) {   // fp32 -> bf16 bits (RNE)
  union { __hip_bfloat16 h; unsigned short u; } c;
  c.h = __float2bfloat16(f);
  return c.u;
}
__device__ __forceinline__ float b2f(unsigned short u) {   // bf16 bits -> fp32
  union { float f; unsigned u; } c; c.u = ((unsigned)u) << 16;
  return c.f;
}
__device__ __forceinline__ short8 ld8(const unsigned short* p) {  // 16B vector load
  union { uint4v u; short8 s; } c;
  c.u = *(const uint4v*)p;
  return c.s;
}
// 2 fp32 -> packed 2x bf16 (one v_cvt_pk_bf16_f32)
__device__ __forceinline__ unsigned cvt2(float a, float b) {
  union { __hip_bfloat162 h; unsigned u; } c;
  c.h = __float22bfloat162_rn(float2{a, b});
  return c.u;
}
// 4 fp32 -> 4 bf16 (two v_cvt_pk_bf16_f32)
__device__ __forceinline__ ushort4v cvt4(floatx4 v) {
  union { unsigned u[2]; ushort4v s; } c;
  c.u[0] = cvt2(v.x, v.y);
  c.u[1] = cvt2(v.z, v.w);
  return c.s;
}

// ---------------------------------------------------------------------------
// Kernel 1: pack fp32 inputs -> bf16 workspace (halves GEMM re-read traffic).
// ---------------------------------------------------------------------------
#define SEG_X   (M_*H_)          // 3145728 (hidden)
#define SEG_XC  (2*SEG_X)        // 6291456 (end of context)
#define SEG_W1  (H_*H_)          // 589824
#define SEG_WE  (SEG_XC + 3*SEG_W1)   // 8060928
#define SEG_BE  (SEG_WE + NTOT)  // 8063232
#define SEG_PE  (SEG_BE + SQ_*DH_)    // 8096000 (pos bf16)

__global__ __launch_bounds__(256) void pack_kernel(
    const float* __restrict__ hid, const float* __restrict__ ctx,
    const float* __restrict__ Wq, const float* __restrict__ Wk, const float* __restrict__ Wv,
    const float* __restrict__ bq, const float* __restrict__ bk, const float* __restrict__ bv,
    const float* __restrict__ pos,
    unsigned short* __restrict__ Xh, unsigned short* __restrict__ Xc,
    unsigned short* __restrict__ Wa, float* __restrict__ Ba,
    unsigned short* __restrict__ Pb)
{
  int i = (blockIdx.x * 256 + threadIdx.x) * 4;
  if (i < SEG_X) {
    floatx4 v = *(const floatx4*)(hid + i);
    *(ushort4v*)(Xh + i) = cvt4(v);
  } else if (i < SEG_XC) {
    int j = i - SEG_X;
    floatx4 v = *(const floatx4*)(ctx + j);
    *(ushort4v*)(Xc + j) = cvt4(v);
  } else if (i < SEG_WE) {
    int j = i - SEG_XC;
    const float* src; int o;
    if (j < SEG_W1)        { src = Wq; o = j; }
    else if (j < 2*SEG_W1) { src = Wk; o = j - SEG_W1; }
    else                   { src = Wv; o = j - 2*SEG_W1; }
    floatx4 v = *(const floatx4*)(src + o);
    *(ushort4v*)(Wa + j) = cvt4(v);
  } else if (i < SEG_BE) {
    int j = i - SEG_WE;
    #pragma unroll
    for (int t = 0; t < 4; ++t) {
      int jj = j + t;
      float v = (jj < H_) ? bq[jj] : (jj < 2*H_) ? bk[jj - H_] : bv[jj - 2*H_];
      Ba[jj] = v;
    }
  } else if (i < SEG_PE) {
    int j = i - SEG_BE;
    floatx4 v = *(const floatx4*)(pos + j);
    *(ushort4v*)(Pb + j) = cvt4(v);
  }
}

// ---------------------------------------------------------------------------
// Kernel 2: fused QKV projection GEMM (bf16 MFMA), M=4096 x N=2304 x K=768.
//   r0 structure (best measured): register-staged LDS, padded [128][72]
//   (conflict-light ds_read_b128), next-tile loads prefetched during MFMA
//   phase. XCD-swizzled tile mapping. cvt_pk epilogues.
//   Blocks 576..591: side GEMM P2 = pos . pos^T (512x512, K=64), f32 out.
//   P2 removes half of the attention kernel's QK MFMAs.
// ---------------------------------------------------------------------------
__global__ __launch_bounds__(256) void qkv_gemm(
    const unsigned short* __restrict__ Xh, const unsigned short* __restrict__ Xc,
    const unsigned short* __restrict__ W,  const float* __restrict__ bias,
    const unsigned short* __restrict__ Pb,
    unsigned short* __restrict__ qw, unsigned short* __restrict__ kw,
    unsigned short* __restrict__ vt, float* __restrict__ P2)
{
  __shared__ unsigned short As[128][72];
  __shared__ unsigned short Bs[128][72];

  int bx = blockIdx.x;
  int tid = threadIdx.x;
  int lane = tid & 63, wave = tid >> 6;
  int lc16 = lane & 15, quad = lane >> 4, kk = quad * 8;

  if (bx >= 576) {
    // ---- P2 = pos . pos^T : 16 blocks, 128x128 tile each, K=64, no LDS ----
    int pb = bx - 576;
    int q0 = (pb >> 2) * 128, k0 = (pb & 3) * 128;
    int wq = (wave & 1) * 64, wk = (wave >> 1) * 64;
    short8 aqf[4][2], akf[4][2];
    #pragma unroll
    for (int i = 0; i < 4; ++i) {
      const unsigned short* qr = Pb + (q0 + wq + i * 16 + lc16) * DH_;
      const unsigned short* kr = Pb + (k0 + wk + i * 16 + lc16) * DH_;
      aqf[i][0] = ld8(qr + kk);      aqf[i][1] = ld8(qr + 32 + kk);
      akf[i][0] = ld8(kr + kk);      akf[i][1] = ld8(kr + 32 + kk);
    }
    #pragma unroll
    for (int i = 0; i < 4; ++i) {
      #pragma unroll
      for (int jt = 0; jt < 4; ++jt) {
        floatx4 acc2 = (floatx4){0.f, 0.f, 0.f, 0.f};
        acc2 = MFMA16(aqf[i][0], akf[jt][0], acc2);
        acc2 = MFMA16(aqf[i][1], akf[jt][1], acc2);
        // D[row = q-in-tile = quad*4+r][col = k-in-tile = lc16]
        #pragma unroll
        for (int r = 0; r < 4; ++r)
          P2[(size_t)(q0 + wq + i * 16 + quad * 4 + r) * SK_ + (k0 + wk + jt * 16 + lc16)] = acc2[r];
      }
    }
    return;
  }

  int xcd = bx & 7, j = bx >> 3;            // j in [0,72)
  int bm = (xcd >> 1) * 8 + j / 9;          // 32 m-tiles
  int bn = (xcd & 1) * 9 + j % 9;           // 18 n-tiles
  const unsigned short* X = (bn < 6) ? Xh : Xc;
  bool isV = (bn >= 12);
  int m0 = bm * 128, n0 = bn * 128;

  int wm = (wave & 1) * 64, wn = (wave >> 1) * 64;
  int srow = tid >> 3, sch = (tid & 7) * 8;   // staging: 32 rows x 8 chunks of 8

  unsigned short (*TA)[72] = isV ? As : Bs;
  unsigned short (*TB)[72] = isV ? Bs : As;
  int oa = isV ? wm : wn;
  int ob = isV ? wn : wm;

  floatx4 acc[4][4];
  #pragma unroll
  for (int i = 0; i < 4; ++i)
    #pragma unroll
    for (int jj = 0; jj < 4; ++jj) acc[i][jj] = (floatx4){0.f, 0.f, 0.f, 0.f};

  uint4v a[4], b[4];
  #pragma unroll
  for (int rp = 0; rp < 4; ++rp) {
    a[rp] = *(const uint4v*)&X[(m0 + srow + rp * 32) * H_ + sch];
    b[rp] = *(const uint4v*)&W[(n0 + srow + rp * 32) * H_ + sch];
  }

  for (int k0 = 0; k0 < H_; k0 += 64) {
    __syncthreads();
    #pragma unroll
    for (int rp = 0; rp < 4; ++rp) {
      *(uint4v*)&As[srow + rp * 32][sch] = a[rp];
      *(uint4v*)&Bs[srow + rp * 32][sch] = b[rp];
    }
    __syncthreads();

    if (k0 + 64 < H_) {   // prefetch next K-tile during MFMA phase
      #pragma unroll
      for (int rp = 0; rp < 4; ++rp) {
        a[rp] = *(const uint4v*)&X[(m0 + srow + rp * 32) * H_ + k0 + 64 + sch];
        b[rp] = *(const uint4v*)&W[(n0 + srow + rp * 32) * H_ + k0 + 64 + sch];
      }
    }

    #pragma unroll
    for (int s = 0; s < 2; ++s) {
      short8 af[4], bf[4];
      #pragma unroll
      for (int i = 0; i < 4; ++i) af[i] = ld8(&TA[oa + i * 16 + lc16][s * 32 + kk]);
      #pragma unroll
      for (int i = 0; i < 4; ++i) bf[i] = ld8(&TB[ob + i * 16 + lc16][s * 32 + kk]);
      #pragma unroll
      for (int mi = 0; mi < 4; ++mi)
        #pragma unroll
        for (int ni = 0; ni < 4; ++ni)
          acc[mi][ni] = MFMA16(af[mi], bf[ni], acc[mi][ni]);
    }
  }

  if (!isV) {
    #pragma unroll
    for (int mi = 0; mi < 4; ++mi) {
      #pragma unroll
      for (int ni = 0; ni < 4; ++ni) {
        int gn0 = n0 + wn + mi * 16 + quad * 4;     // 4 consecutive features
        int gs  = m0 + wm + ni * 16 + lc16;         // sequence index
        int bidx = gs >> 9, s0 = gs & 511;
        floatx4 bv4 = *(const floatx4*)&bias[gn0];
        if (gn0 < H_) {                              // Q
          int h = gn0 >> 6, d0 = gn0 & 63;
          floatx4 v;
          #pragma unroll
          for (int r = 0; r < 4; ++r) v[r] = acc[mi][ni][r] + bv4[r];
          *(ushort4v*)(qw + (((bidx * NH_ + h) << 9) + s0) * DH_ + d0) = cvt4(v);
        } else {                                     // K (+ bf16 pos_k)
          int g = gn0 - H_;
          int h = g >> 6, d0 = g & 63;
          ushort4v pk = *(const ushort4v*)(Pb + s0 * DH_ + d0);
          floatx4 v;
          #pragma unroll
          for (int r = 0; r < 4; ++r) v[r] = acc[mi][ni][r] + bv4[r] + b2f(pk[r]);
          *(ushort4v*)(kw + (((bidx * NH_ + h) << 9) + s0) * DH_ + d0) = cvt4(v);
        }
      }
    }
  } else {
    #pragma unroll
    for (int mi = 0; mi < 4; ++mi) {
      #pragma unroll
      for (int ni = 0; ni < 4; ++ni) {
        int gm0 = m0 + wm + mi * 16 + quad * 4;
        int gn  = n0 + wn + ni * 16 + lc16;
        float bvs = bias[gn];
        int bidx = gm0 >> 9, s0 = gm0 & 511;
        int g = gn - 2 * H_;
        int h = g >> 6, d = g & 63;
        floatx4 v;
        #pragma unroll
        for (int r = 0; r < 4; ++r) v[r] = acc[mi][ni][r] + bvs;
        *(ushort4v*)(vt + ((bidx * NH_ + h) * DH_ + d) * SK_ + s0) = cvt4(v);
      }
    }
  }
}

// ---------------------------------------------------------------------------
// Kernel 3: attention. scores = q.(k+pos_k) [kw] + pos_q.pos_k [P2, precomp].
//   QK accumulator is SEEDED from P2 (software-pipelined float4 loads, one
//   step ahead) -> QK MFMAs halve vs previous rounds (2 per step, not 4),
//   no pos fragments held. Softmax fused into QK epilogue (no max pass).
//   Double-buffered prob chunks; K frag loads pipelined one step ahead;
//   V frags issued before QK phase; setprio around MFMA clusters.
// ---------------------------------------------------------------------------
#define SCALE2 0.18033688011112042f   // (1/8) * log2(e)
#define CPAD 136                      // chunk row stride (128 + 8)

__global__ __launch_bounds__(256) void attn_kernel(
    const unsigned short* __restrict__ qw, const unsigned short* __restrict__ kw,
    const unsigned short* __restrict__ vt, const float* __restrict__ P2,
    const int* __restrict__ mask, float* __restrict__ out)
{
  __shared__ unsigned short Sc[2][64][CPAD];  // bf16 probs, double-buffered chunks
  __shared__ float mb2[SK_];                  // mask bias in exp2 domain
  __shared__ float red[64][4];                // per-wave row-sum partials

  int bx = blockIdx.x;
  int bh = bx % 96, qt = bx / 96;          // XCD-friendly: bx%8 == bh%8
  int b = bh / NH_, h = bh - b * NH_;
  int tid = threadIdx.x, lane = tid & 63, wave = tid >> 6;
  int lc16 = lane & 15, quad = lane >> 4, kk = quad * 8;

  for (int i = tid; i < SK_; i += 256)
    mb2[i] = mask[(b << 9) + i] ? 0.0f : -100000.0f;

  // Q frags (held all QK phases): 4 row-tiles x 2
  const unsigned short* qbase = qw + ((bh << 9) + qt * 64) * DH_;
  short8 aq[4][2];
  #pragma unroll
  for (int rt = 0; rt < 4; ++rt) {
    const unsigned short* qr = qbase + (rt * 16 + lc16) * DH_;
    aq[rt][0] = ld8(qr + kk);
    aq[rt][1] = ld8(qr + 32 + kk);
  }

  const unsigned short* kwb = kw + ((bh << 9)) * DH_;
  const unsigned short* vb0 = vt + (bh * DH_ + wave * 16 + lc16) * SK_;
  const float* p2b = P2 + (size_t)(qt * 64 + lc16) * SK_ + quad * 4;  // + rt*16*SK_ + kcol
  float rs[4] = {0.f, 0.f, 0.f, 0.f};      // per-lane row-sum partials
  floatx4 o[4];
  #pragma unroll
  for (int i = 0; i < 4; ++i) o[i] = (floatx4){0.f, 0.f, 0.f, 0.f};

  // prefetch K frags + P2 seeds for step 0
  short8 cb0, cb1, nb0, nb1;
  floatx4 pc[4], pn[4];
  {
    int kcol = wave * 32;
    const unsigned short* kb = kwb + kcol * DH_;
    cb0 = ld8(kb + lc16 * DH_ + kk);
    cb1 = ld8(kb + lc16 * DH_ + 32 + kk);
    #pragma unroll
    for (int rt = 0; rt < 4; ++rt)
      pc[rt] = *(const floatx4*)(p2b + rt * 16 * SK_ + kcol);
  }

  __syncthreads();   // mb2 ready

  for (int chunk = 0; chunk < 4; ++chunk) {
    unsigned short (*S)[CPAD] = Sc[chunk & 1];

    // V frags for this chunk: issue early, consumed after the barrier
    short8 vf[4];
    #pragma unroll
    for (int ks = 0; ks < 4; ++ks) vf[ks] = ld8(vb0 + chunk * 128 + ks * 32 + kk);

    // ---- QK + exp: wave owns chunk-local cols [wave*32, wave*32+32) ----
    #pragma unroll
    for (int ct = 0; ct < 2; ++ct) {
      int s = chunk * 2 + ct;
      if (s < 7) {   // prefetch next step's K frags + P2 seeds
        int kcol = ((s + 1) >> 1) * 128 + wave * 32 + ((s + 1) & 1) * 16;
        const unsigned short* kb = kwb + kcol * DH_;
        nb0 = ld8(kb + lc16 * DH_ + kk);
        nb1 = ld8(kb + lc16 * DH_ + 32 + kk);
        #pragma unroll
        for (int rt = 0; rt < 4; ++rt)
          pn[rt] = *(const floatx4*)(p2b + rt * 16 * SK_ + kcol);
      }
      int kcol = chunk * 128 + wave * 32 + ct * 16;
      floatx4 mk = *(const floatx4*)&mb2[kcol + quad * 4];
      floatx4 c[4];
      __builtin_amdgcn_s_setprio(1);
      #pragma unroll
      for (int rt = 0; rt < 4; ++rt) {
        c[rt] = pc[rt];                          // seed with pos_q . pos_k
        c[rt] = MFMA16(cb0, aq[rt][0], c[rt]);   // A=K-tile, B=Q-rows
        c[rt] = MFMA16(cb1, aq[rt][1], c[rt]);
      }
      __builtin_amdgcn_s_setprio(0);
      int lcol = wave * 32 + ct * 16 + quad * 4;   // chunk-local col base
      #pragma unroll
      for (int rt = 0; rt < 4; ++rt) {
        floatx4 ev;
        float sum = 0.f;
        #pragma unroll
        for (int r = 0; r < 4; ++r) {
          float e = __builtin_exp2f(c[rt][r] * SCALE2 + mk[r]);
          sum += e;
          ev[r] = e;
        }
        rs[rt] += sum;
        *(ushort4v*)&S[rt * 16 + lc16][lcol] = cvt4(ev);
      }
      cb0 = nb0; cb1 = nb1;
      #pragma unroll
      for (int rt = 0; rt < 4; ++rt) pc[rt] = pn[rt];
    }
    __syncthreads();   // probs chunk ready (also: prior chunk fully consumed)

    // ---- PV over this chunk: wave owns d-slice [wave*16, +16) ----
    __builtin_amdgcn_s_setprio(1);
    #pragma unroll
    for (int ks = 0; ks < 4; ++ks) {
      #pragma unroll
      for (int rt = 0; rt < 4; ++rt) {
        short8 pa = ld8(&S[rt * 16 + lc16][ks * 32 + kk]);
        o[rt] = MFMA16(pa, vf[ks], o[rt]);
      }
    }
    __builtin_amdgcn_s_setprio(0);
    // no second barrier: next chunk writes the other Sc buffer
  }

  // ---- row-sum: reduce across quads, then across waves via LDS ----
  #pragma unroll
  for (int rt = 0; rt < 4; ++rt) {
    rs[rt] += __shfl_xor(rs[rt], 16, 64);
    rs[rt] += __shfl_xor(rs[rt], 32, 64);
  }
  if (quad == 0) {
    #pragma unroll
    for (int rt = 0; rt < 4; ++rt) red[rt * 16 + lc16][wave] = rs[rt];
  }
  __syncthreads();

  #pragma unroll
  for (int rt = 0; rt < 4; ++rt) {
    #pragma unroll
    for (int r = 0; r < 4; ++r) {
      int sl = rt * 16 + quad * 4 + r;
      float inv = 1.0f / (red[sl][0] + red[sl][1] + red[sl][2] + red[sl][3]);
      int s = qt * 64 + sl;
      out[((b << 9) + s) * H_ + h * DH_ + wave * 16 + lc16] = o[rt][r] * inv;
    }
  }
}

// ---------------------------------------------------------------------------
// host launcher
// ---------------------------------------------------------------------------
extern "C" void kernel_launch(void* const* d_in, const int* in_sizes, int n_in,
                              void* d_out, int out_size, void* d_ws, size_t ws_size,
                              hipStream_t stream) {
  (void)in_sizes; (void)n_in; (void)out_size; (void)ws_size;
  const float* hid  = (const float*)d_in[0];
  const float* ctx  = (const float*)d_in[1];
  const int*   mask = (const int*)d_in[2];
  const float* Wq   = (const float*)d_in[3];
  const float* bq   = (const float*)d_in[4];
  const float* Wk   = (const float*)d_in[5];
  const float* bk   = (const float*)d_in[6];
  const float* Wv   = (const float*)d_in[7];
  const float* bv   = (const float*)d_in[8];
  const float* pos  = (const float*)d_in[9];

  char* ws = (char*)d_ws;
  size_t off = 0;
  auto alloc = [&](size_t bytes) { char* p = ws + off; off = (off + bytes + 255) & ~(size_t)255; return p; };
  unsigned short* Xh = (unsigned short*)alloc((size_t)SEG_X * 2);
  unsigned short* Xc = (unsigned short*)alloc((size_t)SEG_X * 2);
  unsigned short* Wa = (unsigned short*)alloc((size_t)3 * SEG_W1 * 2);
  float*          Ba = (float*)alloc((size_t)NTOT * 4);
  unsigned short* qw = (unsigned short*)alloc((size_t)BH_ * SQ_ * DH_ * 2);
  unsigned short* kw = (unsigned short*)alloc((size_t)BH_ * SK_ * DH_ * 2);
  unsigned short* vt = (unsigned short*)alloc((size_t)BH_ * DH_ * SK_ * 2);
  unsigned short* Pb = (unsigned short*)alloc((size_t)SQ_ * DH_ * 2);
  float*          P2 = (float*)alloc((size_t)SQ_ * SK_ * 4);

  int pack_blocks = (SEG_PE / 4 + 255) / 256;
  pack_kernel<<<pack_blocks, 256, 0, stream>>>(hid, ctx, Wq, Wk, Wv, bq, bk, bv, pos, Xh, Xc, Wa, Ba, Pb);
  qkv_gemm<<<32 * 18 + 16, 256, 0, stream>>>(Xh, Xc, Wa, Ba, Pb, qw, kw, vt, P2);
  attn_kernel<<<BH_ * 8, 256, 0, stream>>>(qw, kw, vt, P2, mask, (float*)d_out);
}